// Round 7
// baseline (74.056 us; speedup 1.0000x reference)
//
#include <hip/hip_runtime.h>
#include <hip/hip_bf16.h>

// DIAGNOSTIC ROUND 2: same kernels as R6, but internally rep-looped
// (proj x16, gather x8, idempotent, memory-clobber per rep) so both
// dispatches exceed the ~41us harness fills and land in rocprof top-5
// WITH counters. dur_us this round is sacrificial.
#define G_TOT   16
#define G_OUT   15
#define NNODES  256
#define NEDGES  4096
#define FEAT    64
#define NN      (NNODES * NNODES)
#define EDGES_TOT (G_OUT * NEDGES)                // 61440
#define NTILES  (EDGES_TOT / 16)                  // 3840

typedef __attribute__((ext_vector_type(8))) short short8;
typedef __attribute__((ext_vector_type(4))) float f32x4;
typedef __attribute__((ext_vector_type(2))) int   i32x2;

__device__ __forceinline__ short f2bf(float f) {
    __hip_bfloat16 h = __float2bfloat16(f);
    return *reinterpret_cast<short*>(&h);
}
__device__ __forceinline__ float bf2f(short b) {
    return __uint_as_float(((unsigned)(unsigned short)b) << 16);
}
__device__ __forceinline__ short8 cvt8(f32x4 a, f32x4 b) {
    short8 r;
    r[0] = f2bf(a.x); r[1] = f2bf(a.y); r[2] = f2bf(a.z); r[3] = f2bf(a.w);
    r[4] = f2bf(b.x); r[5] = f2bf(b.y); r[6] = f2bf(b.z); r[7] = f2bf(b.w);
    return r;
}

__global__ __launch_bounds__(256) void pe_proj_mfma(const float* __restrict__ ef,
                                                    const float* __restrict__ emb,
                                                    short* __restrict__ projb,
                                                    int reps) {
    int wave = (blockIdx.x * 256 + threadIdx.x) >> 6;
    int lane = threadIdx.x & 63;
    int rc   = lane & 15;
    int kg   = lane >> 4;
    int e0   = wave << 4;

    for (int rep = 0; rep < reps; ++rep) {
        const float* arow = ef  + (size_t)(e0 + rc) * FEAT + kg * 8;
        const float* brow = emb + (size_t)rc * FEAT + kg * 8;

        f32x4 a0 = __builtin_nontemporal_load((const f32x4*)(arow));
        f32x4 a1 = __builtin_nontemporal_load((const f32x4*)(arow + 4));
        f32x4 a2 = __builtin_nontemporal_load((const f32x4*)(arow + 32));
        f32x4 a3 = __builtin_nontemporal_load((const f32x4*)(arow + 36));
        f32x4 b0 = *(const f32x4*)(brow);
        f32x4 b1 = *(const f32x4*)(brow + 4);
        f32x4 b2 = *(const f32x4*)(brow + 32);
        f32x4 b3 = *(const f32x4*)(brow + 36);

        short8 A0 = cvt8(a0, a1), A1 = cvt8(a2, a3);
        short8 B0 = cvt8(b0, b1), B1 = cvt8(b2, b3);

        f32x4 c = (f32x4)(0.f);
        c = __builtin_amdgcn_mfma_f32_16x16x32_bf16(A0, B0, c, 0, 0, 0);
        c = __builtin_amdgcn_mfma_f32_16x16x32_bf16(A1, B1, c, 0, 0, 0);

#pragma unroll
        for (int r = 0; r < 4; ++r)
            projb[(size_t)(e0 + kg * 4 + r) * 16 + rc] = f2bf(c[r]);
        asm volatile("" ::: "memory");   // force re-issue each rep
    }
}

__global__ __launch_bounds__(256) void pe_gather(const i32x2* __restrict__ path,
                                                 const short8* __restrict__ projb,
                                                 f32x4* __restrict__ out,
                                                 int reps) {
    int pix = blockIdx.x * 256 + threadIdx.x;
    int g   = pix >> 16;
    for (int rep = 0; rep < reps; ++rep) {
        f32x4 lo, hi;
        if (g == G_OUT) {
            lo = hi = (f32x4)(-1000.f);
        } else {
            i32x2 p = path[pix + NN];
            short8 u0 = (short8)(short)0, u1 = (short8)(short)0;
            if (p.x >= 0) u0 = projb[(size_t)(g * NEDGES + p.x) * 2];
            float scale = 1.0f;
            if (p.y >= 0) { u1 = projb[(size_t)(g * NEDGES + p.y) * 2 + 1]; scale = 0.5f; }
            float v[8];
#pragma unroll
            for (int j = 0; j < 8; ++j)
                v[j] = (bf2f(u0[j]) + bf2f(u1[j])) * scale;
            lo = (f32x4){v[0], v[1], v[2], v[3]};
            hi = (f32x4){v[4], v[5], v[6], v[7]};
        }
        out[(size_t)pix * 2]     = lo;
        out[(size_t)pix * 2 + 1] = hi;
        asm volatile("" ::: "memory");   // force re-issue each rep
    }
}

extern "C" void kernel_launch(void* const* d_in, const int* in_sizes, int n_in,
                              void* d_out, int out_size, void* d_ws, size_t ws_size,
                              hipStream_t stream) {
    const float* ef   = (const float*)d_in[0];
    const float* emb  = (const float*)d_in[1];
    const int*   path = (const int*)d_in[3];
    float*       out  = (float*)d_out;
    short*       projb = (short*)d_ws;

    pe_proj_mfma<<<NTILES / 4, 256, 0, stream>>>(ef, emb, projb, 16);
    pe_gather<<<(G_TOT * NN) / 256, 256, 0, stream>>>(
        (const i32x2*)path, (const short8*)projb, (f32x4*)out, 8);
}